// Round 7
// baseline (2234.519 us; speedup 1.0000x reference)
//
#include <hip/hip_runtime.h>

#define L_STEPS 1000
#define BATCH   1024
#define RECF    112   // floats per (t,r) record: [0:96) s1p/s2p interleaved, [96:112) ihp

__device__ __forceinline__ float frcp(float x)  { return __builtin_amdgcn_rcpf(x); }
__device__ __forceinline__ float fsig(float x)  { return frcp(1.0f + __expf(-x)); }
__device__ __forceinline__ float ftanh(float x) { return 1.0f - 2.0f * frcp(__expf(2.0f * x) + 1.0f); }

// quad_perm DPP cross-lane adds (lanes within each 4-lane group)
__device__ __forceinline__ float qxor1(float x) {
    return __int_as_float(__builtin_amdgcn_update_dpp(0, __float_as_int(x), 0xB1, 0xF, 0xF, true));
}
__device__ __forceinline__ float qxor2(float x) {
    return __int_as_float(__builtin_amdgcn_update_dpp(0, __float_as_int(x), 0x4E, 0xF, 0xF, true));
}

#define FMA4(vv, W, base, A) do { \
    A = fmaf((vv).x, W[(base)+0], A); \
    A = fmaf((vv).y, W[(base)+1], A); \
    A = fmaf((vv).z, W[(base)+2], A); \
    A = fmaf((vv).w, W[(base)+3], A); } while (0)

// ===================== Kernel A: parallel precompute (one time-chunk) =====================
// grid (BATCH/128, T_chunk), block 128. Global step = t0 + blockIdx.y; record index is LOCAL.
__global__ __launch_bounds__(128) void vrnn_pre(
    const float* __restrict__ ext, const float* __restrict__ obs,
    const float* __restrict__ puW1, const float* __restrict__ pub1,
    const float* __restrict__ puW2, const float* __restrict__ pub2,
    const float* __restrict__ pxW1, const float* __restrict__ pxb1,
    const float* __restrict__ pxW2, const float* __restrict__ pxb2,
    const float* __restrict__ poW1, const float* __restrict__ pob1,
    const float* __restrict__ poW2, const float* __restrict__ pob2,
    const float* __restrict__ Wih, const float* __restrict__ bih,
    const float* __restrict__ bhh,
    float* __restrict__ rec, int t0)
{
    const int j  = threadIdx.x;
    const int rc = blockIdx.x * 128;
    const int tl = blockIdx.y;                 // local step in chunk

    __shared__ float wsm[768];        // px/pu weights+biases staged
    __shared__ float xu[128][36];     // xe|ue per row (padded stride)

    // offsets: PX1=0(64) PX2=64(256) PU1=320(128) PU2=448(256) BX1=704 BX2=720 BU1=736 BU2=752
    for (int i = j; i < 64;  i += 128) wsm[0   + i] = pxW1[i];
    for (int i = j; i < 256; i += 128) wsm[64  + i] = pxW2[i];
    for (int i = j; i < 128; i += 128) wsm[320 + i] = puW1[i];
    for (int i = j; i < 256; i += 128) wsm[448 + i] = puW2[i];
    if (j < 16) {
        wsm[704 + j] = pxb1[j]; wsm[720 + j] = pxb2[j];
        wsm[736 + j] = pub1[j]; wsm[752 + j] = pub2[j];
    }
    __syncthreads();

    // ---- phase 1: xe/ue for row r = rc + j at global step t0+tl ----
    {
        const size_t row = (size_t)(t0 + tl) * BATCH + rc + j;
        const float* o = obs + row * 4;
        const float* e = ext + row * 8;
        float ob[4], ex[8];
        #pragma unroll
        for (int k = 0; k < 4; ++k) ob[k] = o[k];
        #pragma unroll
        for (int k = 0; k < 8; ++k) ex[k] = e[k];

        float t1[16];
        #pragma unroll
        for (int c = 0; c < 16; ++c) {
            float a = wsm[704 + c];
            #pragma unroll
            for (int k = 0; k < 4; ++k) a = fmaf(ob[k], wsm[0 + k * 16 + c], a);
            t1[c] = fmaxf(a, 0.0f);
        }
        #pragma unroll
        for (int c = 0; c < 16; ++c) {
            float a = wsm[720 + c];
            #pragma unroll
            for (int k = 0; k < 16; ++k) a = fmaf(t1[k], wsm[64 + k * 16 + c], a);
            xu[j][c] = fmaxf(a, 0.0f);                    // xe
        }
        #pragma unroll
        for (int c = 0; c < 16; ++c) {
            float a = wsm[736 + c];
            #pragma unroll
            for (int k = 0; k < 8; ++k) a = fmaf(ex[k], wsm[320 + k * 16 + c], a);
            t1[c] = fmaxf(a, 0.0f);
        }
        #pragma unroll
        for (int c = 0; c < 16; ++c) {
            float a = wsm[752 + c];
            #pragma unroll
            for (int k = 0; k < 16; ++k) a = fmaf(t1[k], wsm[448 + k * 16 + c], a);
            xu[j][16 + c] = fmaxf(a, 0.0f);               // ue
        }
    }

    // ---- phase 2: weight column for record element j (j < 112) ----
    float wc[32]; float bias = 0.0f;
    if (j < 96) {
        const int c = j >> 1;
        const float* W = (j & 1) ? poW2 : poW1;
        bias = (j & 1) ? pob2[c] : pob1[c];
        #pragma unroll
        for (int k = 0; k < 32; ++k) wc[k] = W[k * 48 + c];
    } else if (j < 112) {
        const int c = j - 96;
        bias = bih[c] + bhh[c];
        #pragma unroll
        for (int k = 0; k < 32; ++k) wc[k] = Wih[k * 16 + c];
    }
    __syncthreads();

    if (j < 112) {
        float* rb = rec + ((size_t)tl * BATCH + rc) * RECF + j;
        for (int r = 0; r < 128; ++r) {
            const float4* x4 = (const float4*)&xu[r][0];
            float a = bias;
            #pragma unroll
            for (int q = 0; q < 8; ++q) { float4 v = x4[q]; FMA4(v, wc, 4 * q, a); }
            rb[(size_t)r * RECF] = a;
        }
    }
}

// ===================== Kernel B: register-only serial scan (one time-chunk) =====================
__global__ __launch_bounds__(64, 1) void vrnn_scan2(
    const float* __restrict__ rec, float* wsh, const float* __restrict__ eps,
    const float* __restrict__ poW1, const float* __restrict__ poW2,
    const float* __restrict__ Wmu, const float* __restrict__ bmu,
    const float* __restrict__ Wls, const float* __restrict__ bls,
    const float* __restrict__ pzW1, const float* __restrict__ pzb1,
    const float* __restrict__ pzW2, const float* __restrict__ pzb2,
    const float* __restrict__ Wih, const float* __restrict__ Whh,
    float* __restrict__ out, int t0, int T)
{
    const int l   = threadIdx.x;
    const int r   = blockIdx.x;
    const int idx = l >> 2;
    const int p   = l & 3;

    // ---- weights -> registers ----
    const int cl = (l < 48) ? l : 47;            // safe dummy col for lanes 48-63
    float wAh[16], wBh[16];
    #pragma unroll
    for (int k = 0; k < 16; ++k) {
        wAh[k] = poW1[(32 + k) * 48 + cl];
        wBh[k] = poW2[(32 + k) * 48 + cl];
    }
    const int hm = idx & 7;
    const float* WH = (idx < 8) ? Wmu : Wls;
    float whead[12];
    #pragma unroll
    for (int i = 0; i < 12; ++i) whead[i] = WH[(12 * p + i) * 8 + hm];
    const float bhead = (idx < 8) ? bmu[hm] : bls[hm];

    float wr[8];
    #pragma unroll
    for (int i = 0; i < 8; ++i)
        wr[i] = (p < 2) ? Wih[(32 + 8 * (p & 1) + i) * 16 + idx]
                        : Whh[(8 * (p & 1) + i) * 16 + idx];

    const float wz1a = pzW1[(2 * p) * 16 + idx];
    const float wz1b = pzW1[(2 * p + 1) * 16 + idx];
    const float bz1  = pzb1[idx];
    float wz2[4];
    #pragma unroll
    for (int i = 0; i < 4; ++i) wz2[i] = pzW2[(4 * p + i) * 16 + idx];
    const float bz2 = pzb2[idx];

    // ---- stream pointers (record index local to chunk; eps global) ----
    const float* recp = rec + (size_t)r * RECF + ((l < 48) ? 2 * l : 48 + l);
    const size_t rstride = (size_t)BATCH * RECF;
    const float* epsp = eps + ((size_t)t0 * BATCH + r) * 8 + (l & 7);

    float2 f2 = make_float2(0.0f, 0.0f); float d1 = 0.0f;
    if (l < 48) f2 = *(const float2*)recp; else d1 = *recp;
    float ev = *epsp;
    recp += rstride; epsp += (size_t)8 * BATCH;

    float* pout = out + (size_t)t0 * BATCH * 8
                      + ((idx < 8) ? ((size_t)r * 8 + idx)
                                   : ((size_t)L_STEPS * BATCH * 8 + (size_t)r * 8 + (idx - 8)));

    // ---- h carry-in ----
    float hn = (t0 == 0) ? 0.0f : wsh[r * 16 + idx];
    float h[16];
    #pragma unroll
    for (int k = 0; k < 16; ++k) h[k] = 0.0f;

    for (int t = 0; t < T; ++t) {
        const float s1p = f2.x, s2p = f2.y;
        const float ihpv = d1, epsv = ev;

        // issue next-step prefetch (independent of chain)
        float2 nf2 = make_float2(0.0f, 0.0f); float nd1 = 0.0f;
        if (l < 48) nf2 = *(const float2*)recp; else nd1 = *recp;
        float nev = *epsp;
        recp += (t < T - 2) ? rstride : 0;
        epsp += ((t0 + t) < L_STEPS - 2) ? (size_t)8 * BATCH : 0;

        // off-critical-path gathers (issue early)
        const float ihg = __shfl(ihpv, 48 + idx);       // ihp[idx] from lanes 48-63
        const float eg  = __shfl(epsv, idx & 7);        // eps[idx] from lanes 0-7

        // ---- DBlock: sA/sB = precomputed + h-part ----
        #pragma unroll
        for (int k = 0; k < 16; ++k) h[k] = __shfl(hn, 4 * k);   // uniform src -> readlane bcast
        float sA = s1p, sB = s2p;
        #pragma unroll
        for (int k = 0; k < 16; ++k) {
            sA = fmaf(h[k], wAh[k], sA);
            sB = fmaf(h[k], wBh[k], sB);
        }
        const float tt = ftanh(sA) * fsig(sB);          // t48 col l (valid l<48)

        // ---- heads: 4-lane-split dot-48 via shfl gathers ----
        float acc = 0.0f;
        #pragma unroll
        for (int i = 0; i < 12; ++i) acc = fmaf(__shfl(tt, 12 * p + i), whead[i], acc);
        acc += qxor1(acc); acc += qxor2(acc);           // replicated quad sum
        acc += bhead;                                   // mu[idx] (idx<8) | ls[idx-8]
        if (p == 0) *pout = acc;
        pout += (size_t)8 * BATCH;

        // ---- z = mu + exp(0.5 ls)*eps (replicated per quad) ----
        const float other = __shfl(acc, l ^ 32);
        const float zv = fmaf(__expf(0.5f * other), eg, acc);

        // ---- z_e layer 1: 8 -> 16 ----
        float a1 = fmaf(__shfl(zv, 8 * p), wz1a, __shfl(zv, 8 * p + 4) * wz1b);
        a1 += qxor1(a1); a1 += qxor2(a1);
        a1 = fmaxf(a1 + bz1, 0.0f);                     // a1[idx], replicated

        // ---- z_e layer 2: 16 -> 16 ----
        float ze = 0.0f;
        #pragma unroll
        for (int i = 0; i < 4; ++i) ze = fmaf(__shfl(a1, 16 * p + 4 * i), wz2[i], ze);
        ze += qxor1(ze); ze += qxor2(ze);
        ze = fmaxf(ze + bz2, 0.0f);                     // ze[idx], replicated

        // ---- RNN: pre = ihp + ze.Wih[32:48] + h.Whh ----
        float pre = 0.0f;
        #pragma unroll
        for (int i = 0; i < 8; ++i) {
            const float g = __shfl(ze, 4 * (8 * (p & 1) + i));
            const float v = (p < 2) ? g : h[8 * (p & 1) + i];
            pre = fmaf(v, wr[i], pre);
        }
        pre += qxor1(pre); pre += qxor2(pre);
        hn = ftanh(pre + ihg);                          // h'[idx], replicated in all lanes

        f2 = nf2; d1 = nd1; ev = nev;
    }

    // ---- h carry-out / final output ----
    if (t0 + T >= L_STEPS) {
        if (p == 0) out[(size_t)L_STEPS * BATCH * 8 * 2 + (size_t)r * 16 + idx] = hn;
    } else {
        if (p == 0) wsh[r * 16 + idx] = hn;
    }
}

// ===================== Fallback: proven round-2 kernel (ws too small) =====================
__global__ __launch_bounds__(64, 1) void vrnn_scan(
    const float* __restrict__ ext, const float* __restrict__ obs, const float* __restrict__ eps,
    const float* __restrict__ puW1, const float* __restrict__ pub1,
    const float* __restrict__ puW2, const float* __restrict__ pub2,
    const float* __restrict__ pxW1, const float* __restrict__ pxb1,
    const float* __restrict__ pxW2, const float* __restrict__ pxb2,
    const float* __restrict__ pzW1, const float* __restrict__ pzb1,
    const float* __restrict__ pzW2, const float* __restrict__ pzb2,
    const float* __restrict__ poW1, const float* __restrict__ pob1,
    const float* __restrict__ poW2, const float* __restrict__ pob2,
    const float* __restrict__ Wmu, const float* __restrict__ bmu,
    const float* __restrict__ Wls, const float* __restrict__ bls,
    const float* __restrict__ Wih, const float* __restrict__ bih,
    const float* __restrict__ Whh, const float* __restrict__ bhh,
    float* __restrict__ out)
{
    const int l   = threadIdx.x;
    const int r   = blockIdx.x;
    const int idx = l >> 2;
    const int p   = l & 3;

    __shared__ __align__(16) float rawbuf[16];
    __shared__ __align__(16) float epsbuf[8];
    __shared__ __align__(16) float h1buf[32];
    __shared__ __align__(16) float in64[64];
    __shared__ __align__(16) float s2buf[48];
    __shared__ __align__(16) float t48[48];
    __shared__ __align__(16) float zbuf[8];
    __shared__ __align__(16) float ze1buf[16];
    __shared__ float bheadb[16];
    __shared__ float brnnb[16];

    if (l < 16) {
        rawbuf[l]    = 0.0f;
        in64[48 + l] = 0.0f;
        bheadb[l]    = (l < 8) ? bmu[l] : bls[l - 8];
        brnnb[l]     = bih[l] + bhh[l];
    }

    float wA[48]; float biasA;
    {
        const float* baseA;
        if (l < 48) { baseA = poW1 + l;        biasA = pob1[l]; }
        else        { baseA = poW2 + (l - 48); biasA = pob2[l - 48]; }
        #pragma unroll
        for (int k = 0; k < 48; ++k) wA[k] = baseA[k * 48];
    }
    float wB[48]; float biasB;
    {
        const int c = 16 + (l & 31);
        const float* baseB = poW2 + c;
        biasB = pob2[c];
        #pragma unroll
        for (int k = 0; k < 48; ++k) wB[k] = baseB[k * 48];
    }
    float whead[12];
    {
        const float* baseH = (idx < 8) ? (Wmu + idx) : (Wls + (idx - 8));
        #pragma unroll
        for (int i = 0; i < 12; ++i) whead[i] = baseH[(12 * p + i) * 8];
    }
    float wrnn[16];
    {
        #pragma unroll
        for (int i = 0; i < 16; ++i) {
            const int c = 16 * p + i;
            const float a = Wih[min(c, 47) * 16 + idx];
            const float b = Whh[max(c - 48, 0) * 16 + idx];
            wrnn[i] = (c < 48) ? a : b;
        }
    }
    const int j16 = l & 15;
    float wpre1[8], wpre2[16], bpre1, bpre2;
    {
        const bool isx = (l < 16);
        #pragma unroll
        for (int k = 0; k < 8; ++k) {
            const float xv = pxW1[min(k, 3) * 16 + j16];
            const float uv = puW1[k * 16 + j16];
            float v = isx ? xv : uv;
            if (isx && k >= 4) v = 0.0f;
            wpre1[k] = v;
        }
        #pragma unroll
        for (int k = 0; k < 16; ++k) {
            const float xv = pxW2[k * 16 + j16];
            const float uv = puW2[k * 16 + j16];
            wpre2[k] = isx ? xv : uv;
        }
        bpre1 = isx ? pxb1[j16] : pub1[j16];
        bpre2 = isx ? pxb2[j16] : pub2[j16];
    }
    float wpz1[8], wpz2[16], bpz1, bpz2;
    {
        #pragma unroll
        for (int k = 0; k < 8; ++k)  wpz1[k] = pzW1[k * 16 + j16];
        #pragma unroll
        for (int k = 0; k < 16; ++k) wpz2[k] = pzW2[k * 16 + j16];
        bpz1 = pzb1[j16];
        bpz2 = pzb2[j16];
    }

    const float* pin; long pstride;
    if (l < 4)                  { pin = obs + (size_t)r * 4 + l;        pstride = 4 * BATCH; }
    else if (l >= 8 && l < 16)  { pin = ext + (size_t)r * 8 + (l - 8);  pstride = 8 * BATCH; }
    else if (l >= 16 && l < 24) { pin = eps + (size_t)r * 8 + (l - 16); pstride = 8 * BATCH; }
    else                        { pin = obs;                            pstride = 0; }

    float vin = *pin;
    pin += pstride;

    float* pout = out + ((idx < 8) ? ((size_t)r * 8 + idx)
                                   : ((size_t)L_STEPS * BATCH * 8 + (size_t)r * 8 + (idx - 8)));

    __syncthreads();

    float hn = 0.0f;

    for (int t = 0; t < L_STEPS; ++t) {
        if (l < 4 || (l >= 8 && l < 16)) rawbuf[l] = vin;
        if (l >= 16 && l < 24)           epsbuf[l - 16] = vin;
        vin = *pin;
        pin += (t < L_STEPS - 2) ? pstride : 0;

        {
            const float4* rb = (const float4*)(rawbuf + ((l & 16) ? 8 : 0));
            float4 v0 = rb[0], v1 = rb[1];
            float a1 = bpre1;
            FMA4(v0, wpre1, 0, a1);
            FMA4(v1, wpre1, 4, a1);
            a1 = fmaxf(a1, 0.0f);
            if (l < 32) h1buf[l] = a1;
            const float4* hb = (const float4*)(h1buf + ((l & 16) ? 16 : 0));
            float a2 = bpre2;
            #pragma unroll
            for (int q = 0; q < 4; ++q) { float4 v = hb[q]; FMA4(v, wpre2, 4 * q, a2); }
            a2 = fmaxf(a2, 0.0f);
            if (l < 32) in64[l] = a2;
        }

        float sA = biasA, sB = biasB;
        {
            const float4* c4 = (const float4*)in64;
            #pragma unroll
            for (int q = 0; q < 8; ++q) {
                float4 v = c4[q];
                FMA4(v, wA, 4 * q, sA);
                FMA4(v, wB, 4 * q, sB);
            }
            const float4* h4 = (const float4*)(in64 + 48);
            #pragma unroll
            for (int q = 0; q < 4; ++q) {
                float4 v = h4[q];
                FMA4(v, wA, 32 + 4 * q, sA);
                FMA4(v, wB, 32 + 4 * q, sB);
            }
        }
        if (l >= 48) s2buf[l - 48] = sA;
        if (l < 32)  s2buf[16 + l] = sB;
        if (l < 48)  t48[l] = ftanh(sA) * fsig(s2buf[l]);

        float acc = 0.0f;
        {
            const float4* tb = (const float4*)(t48 + 12 * p);
            float4 a0 = tb[0], a1v = tb[1], a2v = tb[2];
            FMA4(a0,  whead, 0, acc);
            FMA4(a1v, whead, 4, acc);
            FMA4(a2v, whead, 8, acc);
        }
        acc += __shfl_xor(acc, 1);
        acc += __shfl_xor(acc, 2);
        acc += bheadb[idx];
        if (p == 0) *pout = acc;
        pout += (size_t)8 * BATCH;

        {
            float lsv = __shfl(acc, l | 32);
            if (l < 32) {
                float z = fmaf(__expf(0.5f * lsv), epsbuf[idx], acc);
                if (p == 0) zbuf[idx] = z;
            }
        }

        {
            const float4* zb = (const float4*)zbuf;
            float4 z0 = zb[0], z1 = zb[1];
            float a1 = bpz1;
            FMA4(z0, wpz1, 0, a1);
            FMA4(z1, wpz1, 4, a1);
            a1 = fmaxf(a1, 0.0f);
            if (l < 16) ze1buf[l] = a1;
            const float4* zeb = (const float4*)ze1buf;
            float a2 = bpz2;
            #pragma unroll
            for (int q = 0; q < 4; ++q) { float4 v = zeb[q]; FMA4(v, wpz2, 4 * q, a2); }
            a2 = fmaxf(a2, 0.0f);
            if (l < 16) in64[32 + l] = a2;
        }

        {
            const float4* ib = (const float4*)(in64 + 16 * p);
            float a = 0.0f;
            #pragma unroll
            for (int q = 0; q < 4; ++q) { float4 v = ib[q]; FMA4(v, wrnn, 4 * q, a); }
            a += __shfl_xor(a, 1);
            a += __shfl_xor(a, 2);
            a += brnnb[idx];
            hn = ftanh(a);
            if (p == 0) in64[48 + idx] = hn;
        }
    }

    if (p == 0) out[(size_t)L_STEPS * BATCH * 8 * 2 + (size_t)r * 16 + idx] = hn;
}

extern "C" void kernel_launch(void* const* d_in, const int* in_sizes, int n_in,
                              void* d_out, int out_size, void* d_ws, size_t ws_size,
                              hipStream_t stream) {
    const float* ext  = (const float*)d_in[0];
    const float* obs  = (const float*)d_in[1];
    const float* eps  = (const float*)d_in[2];
    const float* puW1 = (const float*)d_in[3];  const float* pub1 = (const float*)d_in[4];
    const float* puW2 = (const float*)d_in[5];  const float* pub2 = (const float*)d_in[6];
    const float* pxW1 = (const float*)d_in[7];  const float* pxb1 = (const float*)d_in[8];
    const float* pxW2 = (const float*)d_in[9];  const float* pxb2 = (const float*)d_in[10];
    const float* pzW1 = (const float*)d_in[11]; const float* pzb1 = (const float*)d_in[12];
    const float* pzW2 = (const float*)d_in[13]; const float* pzb2 = (const float*)d_in[14];
    const float* poW1 = (const float*)d_in[15]; const float* pob1 = (const float*)d_in[16];
    const float* poW2 = (const float*)d_in[17]; const float* pob2 = (const float*)d_in[18];
    const float* Wmu  = (const float*)d_in[19]; const float* bmu  = (const float*)d_in[20];
    const float* Wls  = (const float*)d_in[21]; const float* bls  = (const float*)d_in[22];
    const float* Wih  = (const float*)d_in[23]; const float* bih  = (const float*)d_in[24];
    const float* Whh  = (const float*)d_in[25]; const float* bhh  = (const float*)d_in[26];
    float* out = (float*)d_out;

    // chunked workspace: [0, 64KB) h-carry, then per-step records of RECF floats
    const size_t hfloats = (size_t)BATCH * 16;                       // 64 KB
    const size_t perstep = (size_t)BATCH * RECF * sizeof(float);     // 458,752 B
    long tc = 0;
    if (ws_size > hfloats * sizeof(float))
        tc = (long)((ws_size - hfloats * sizeof(float)) / perstep);
    if (tc > L_STEPS) tc = L_STEPS;

    if (tc >= 1) {
        float* wsh = (float*)d_ws;
        float* rec = wsh + hfloats;
        for (int t0 = 0; t0 < L_STEPS; t0 += (int)tc) {
            const int T = (L_STEPS - t0 < (int)tc) ? (L_STEPS - t0) : (int)tc;
            vrnn_pre<<<dim3(BATCH / 128, T), dim3(128), 0, stream>>>(
                ext, obs, puW1, pub1, puW2, pub2, pxW1, pxb1, pxW2, pxb2,
                poW1, pob1, poW2, pob2, Wih, bih, bhh, rec, t0);
            vrnn_scan2<<<dim3(BATCH), dim3(64), 0, stream>>>(
                rec, wsh, eps, poW1, poW2, Wmu, bmu, Wls, bls,
                pzW1, pzb1, pzW2, pzb2, Wih, Whh, out, t0, T);
        }
    } else {
        vrnn_scan<<<dim3(BATCH), dim3(64), 0, stream>>>(
            ext, obs, eps,
            puW1, pub1, puW2, pub2,
            pxW1, pxb1, pxW2, pxb2,
            pzW1, pzb1, pzW2, pzb2,
            poW1, pob1, poW2, pob2,
            Wmu, bmu, Wls, bls,
            Wih, bih, Whh, bhh,
            out);
    }
}

// Round 10
// 2059.471 us; speedup vs baseline: 1.0850x; 1.0850x over previous
//
#include <hip/hip_runtime.h>

#define L_STEPS 1000
#define BATCH   1024
#define RECF    112   // floats per (t,r) record: [0:96) s1p/s2p interleaved, [96:112) ihp

__device__ __forceinline__ float frcp(float x)  { return __builtin_amdgcn_rcpf(x); }
__device__ __forceinline__ float fsig(float x)  { return frcp(1.0f + __expf(-x)); }
__device__ __forceinline__ float ftanh(float x) { return 1.0f - 2.0f * frcp(__expf(2.0f * x) + 1.0f); }
__device__ __forceinline__ float rdlane(float x, int lane) {
    return __int_as_float(__builtin_amdgcn_readlane(__float_as_int(x), lane));
}

// quad_perm DPP cross-lane adds (lanes within each 4-lane group)
__device__ __forceinline__ float qxor1(float x) {
    return __int_as_float(__builtin_amdgcn_update_dpp(0, __float_as_int(x), 0xB1, 0xF, 0xF, true));
}
__device__ __forceinline__ float qxor2(float x) {
    return __int_as_float(__builtin_amdgcn_update_dpp(0, __float_as_int(x), 0x4E, 0xF, 0xF, true));
}

#define FMA4(vv, W, base, A) do { \
    A = fmaf((vv).x, W[(base)+0], A); \
    A = fmaf((vv).y, W[(base)+1], A); \
    A = fmaf((vv).z, W[(base)+2], A); \
    A = fmaf((vv).w, W[(base)+3], A); } while (0)

// ===================== Kernel A: parallel precompute (one time-chunk) =====================
__global__ __launch_bounds__(128) void vrnn_pre(
    const float* __restrict__ ext, const float* __restrict__ obs,
    const float* __restrict__ puW1, const float* __restrict__ pub1,
    const float* __restrict__ puW2, const float* __restrict__ pub2,
    const float* __restrict__ pxW1, const float* __restrict__ pxb1,
    const float* __restrict__ pxW2, const float* __restrict__ pxb2,
    const float* __restrict__ poW1, const float* __restrict__ pob1,
    const float* __restrict__ poW2, const float* __restrict__ pob2,
    const float* __restrict__ Wih, const float* __restrict__ bih,
    const float* __restrict__ bhh,
    float* __restrict__ rec, int t0)
{
    const int j  = threadIdx.x;
    const int rc = blockIdx.x * 128;
    const int tl = blockIdx.y;                 // local step in chunk

    __shared__ float wsm[768];        // px/pu weights+biases staged
    __shared__ float xu[128][36];     // xe|ue per row (padded stride)

    for (int i = j; i < 64;  i += 128) wsm[0   + i] = pxW1[i];
    for (int i = j; i < 256; i += 128) wsm[64  + i] = pxW2[i];
    for (int i = j; i < 128; i += 128) wsm[320 + i] = puW1[i];
    for (int i = j; i < 256; i += 128) wsm[448 + i] = puW2[i];
    if (j < 16) {
        wsm[704 + j] = pxb1[j]; wsm[720 + j] = pxb2[j];
        wsm[736 + j] = pub1[j]; wsm[752 + j] = pub2[j];
    }
    __syncthreads();

    // ---- phase 1: xe/ue for row r = rc + j at global step t0+tl ----
    {
        const size_t row = (size_t)(t0 + tl) * BATCH + rc + j;
        const float* o = obs + row * 4;
        const float* e = ext + row * 8;
        float ob[4], ex[8];
        #pragma unroll
        for (int k = 0; k < 4; ++k) ob[k] = o[k];
        #pragma unroll
        for (int k = 0; k < 8; ++k) ex[k] = e[k];

        float t1[16];
        #pragma unroll
        for (int c = 0; c < 16; ++c) {
            float a = wsm[704 + c];
            #pragma unroll
            for (int k = 0; k < 4; ++k) a = fmaf(ob[k], wsm[0 + k * 16 + c], a);
            t1[c] = fmaxf(a, 0.0f);
        }
        #pragma unroll
        for (int c = 0; c < 16; ++c) {
            float a = wsm[720 + c];
            #pragma unroll
            for (int k = 0; k < 16; ++k) a = fmaf(t1[k], wsm[64 + k * 16 + c], a);
            xu[j][c] = fmaxf(a, 0.0f);                    // xe
        }
        #pragma unroll
        for (int c = 0; c < 16; ++c) {
            float a = wsm[736 + c];
            #pragma unroll
            for (int k = 0; k < 8; ++k) a = fmaf(ex[k], wsm[320 + k * 16 + c], a);
            t1[c] = fmaxf(a, 0.0f);
        }
        #pragma unroll
        for (int c = 0; c < 16; ++c) {
            float a = wsm[752 + c];
            #pragma unroll
            for (int k = 0; k < 16; ++k) a = fmaf(t1[k], wsm[448 + k * 16 + c], a);
            xu[j][16 + c] = fmaxf(a, 0.0f);               // ue
        }
    }

    // ---- phase 2: weight column for record element j (j < 112) ----
    float wc[32]; float bias = 0.0f;
    if (j < 96) {
        const int c = j >> 1;
        const float* W = (j & 1) ? poW2 : poW1;
        bias = (j & 1) ? pob2[c] : pob1[c];
        #pragma unroll
        for (int k = 0; k < 32; ++k) wc[k] = W[k * 48 + c];
    } else if (j < 112) {
        const int c = j - 96;
        bias = bih[c] + bhh[c];
        #pragma unroll
        for (int k = 0; k < 32; ++k) wc[k] = Wih[k * 16 + c];
    }
    __syncthreads();

    if (j < 112) {
        float* rb = rec + ((size_t)tl * BATCH + rc) * RECF + j;
        for (int r = 0; r < 128; ++r) {
            const float4* x4 = (const float4*)&xu[r][0];
            float a = bias;
            #pragma unroll
            for (int q = 0; q < 8; ++q) { float4 v = x4[q]; FMA4(v, wc, 4 * q, a); }
            rb[(size_t)r * RECF] = a;
        }
    }
}

// ===================== Kernel B: scalar-broadcast serial scan (one time-chunk) =====================
__global__ __launch_bounds__(64, 1) void vrnn_scan2(
    const float* __restrict__ rec, float* wsh, const float* __restrict__ eps,
    const float* __restrict__ poW1, const float* __restrict__ poW2,
    const float* __restrict__ Wmu, const float* __restrict__ bmu,
    const float* __restrict__ Wls, const float* __restrict__ bls,
    const float* __restrict__ pzW1, const float* __restrict__ pzb1,
    const float* __restrict__ pzW2, const float* __restrict__ pzb2,
    const float* __restrict__ Wih, const float* __restrict__ Whh,
    float* __restrict__ out, int t0, int T)
{
    const int l   = threadIdx.x;
    const int r   = blockIdx.x;
    const int idx = l >> 2;
    const int p   = l & 3;

    // ---- weights -> registers (all arrays statically indexed only) ----
    const int cl = (l < 48) ? l : 47;            // safe dummy col for lanes 48-63
    float wAh[16], wBh[16];
    #pragma unroll
    for (int k = 0; k < 16; ++k) {
        wAh[k] = poW1[(32 + k) * 48 + cl];
        wBh[k] = poW2[(32 + k) * 48 + cl];
    }
    const int hm = idx & 7;
    const float* WH = (idx < 8) ? Wmu : Wls;
    float whead[12];
    #pragma unroll
    for (int i = 0; i < 12; ++i) whead[i] = WH[(12 * p + i) * 8 + hm];
    const float bhead = (idx < 8) ? bmu[hm] : bls[hm];

    float wr[8];
    #pragma unroll
    for (int i = 0; i < 8; ++i)
        wr[i] = (p < 2) ? Wih[(32 + 8 * (p & 1) + i) * 16 + idx]
                        : Whh[(8 * (p & 1) + i) * 16 + idx];

    // z_e: each lane owns column c16 = l & 15 of both layers
    const int c16 = l & 15;
    float wz1[8];
    #pragma unroll
    for (int k = 0; k < 8; ++k)  wz1[k] = pzW1[k * 16 + c16];
    const float bz1 = pzb1[c16];
    float wz2[16];
    #pragma unroll
    for (int k = 0; k < 16; ++k) wz2[k] = pzW2[k * 16 + c16];
    const float bz2 = pzb2[c16];

    // ---- stream pointers (record index local to chunk; eps global) ----
    const float* recp = rec + (size_t)r * RECF + ((l < 48) ? 2 * l : 48 + l);
    const size_t rstride = (size_t)BATCH * RECF;
    const float* epsp = eps + ((size_t)t0 * BATCH + r) * 8 + (l & 7);

    float2 f2 = make_float2(0.0f, 0.0f); float d1 = 0.0f;
    if (l < 48) f2 = *(const float2*)recp; else d1 = *recp;
    float ev = *epsp;
    recp += rstride; epsp += (size_t)8 * BATCH;

    float* pout = out + (size_t)t0 * BATCH * 8
                      + ((idx < 8) ? ((size_t)r * 8 + idx)
                                   : ((size_t)L_STEPS * BATCH * 8 + (size_t)r * 8 + (idx - 8)));

    // ---- h carry-in: 16 scalar (wave-uniform) values via readlane ----
    float hn = (t0 == 0) ? 0.0f : wsh[r * 16 + idx];
    float hs[16];
    #pragma unroll
    for (int k = 0; k < 16; ++k) hs[k] = rdlane(hn, 4 * k);

    for (int t = 0; t < T; ++t) {
        const float s1p = f2.x, s2p = f2.y;
        const float ihpv = d1, epsv = ev;

        // issue next-step prefetch (independent of chain)
        float2 nf2 = make_float2(0.0f, 0.0f); float nd1 = 0.0f;
        if (l < 48) nf2 = *(const float2*)recp; else nd1 = *recp;
        float nev = *epsp;
        recp += (t < T - 2) ? rstride : 0;
        epsp += ((t0 + t) < L_STEPS - 2) ? (size_t)8 * BATCH : 0;

        // off-critical-path gathers (issue early; latency hidden under DBlock)
        const float ihg = __shfl(ihpv, 48 + idx);       // ihp[idx] from lanes 48-63
        const float eg  = __shfl(epsv, idx & 7);        // eps[idx] from lanes 0-7

        // ---- DBlock: sA/sB = precomputed + h-part (scalar h, no cross-lane) ----
        float sA = s1p, sB = s2p;
        #pragma unroll
        for (int k = 0; k < 16; ++k) {
            sA = fmaf(hs[k], wAh[k], sA);
            sB = fmaf(hs[k], wBh[k], sB);
        }
        const float tt = ftanh(sA) * fsig(sB);          // t48 col l (valid l<48)

        // ---- heads: 4-lane-split dot-48 (shfl gather round) ----
        float acc = 0.0f;
        #pragma unroll
        for (int i = 0; i < 12; ++i) acc = fmaf(__shfl(tt, 12 * p + i), whead[i], acc);
        acc += qxor1(acc); acc += qxor2(acc);
        acc += bhead;                                   // mu[idx] (idx<8) | ls[idx-8]
        if (p == 0) *pout = acc;
        pout += (size_t)8 * BATCH;

        // ---- z = mu + exp(0.5 ls)*eps (valid lanes < 32) ----
        const float other = __shfl(acc, l ^ 32);
        const float zv = fmaf(__expf(0.5f * other), eg, acc);
        float sz[8];
        #pragma unroll
        for (int j = 0; j < 8; ++j) sz[j] = rdlane(zv, 4 * j);   // z -> scalars

        // ---- z_e layer 1: per-lane full dot over scalar z (col c16) ----
        float a1 = bz1;
        #pragma unroll
        for (int k = 0; k < 8; ++k) a1 = fmaf(sz[k], wz1[k], a1);
        a1 = fmaxf(a1, 0.0f);
        float sa[16];
        #pragma unroll
        for (int j = 0; j < 16; ++j) sa[j] = rdlane(a1, j);      // a1 -> scalars

        // ---- z_e layer 2: per-lane full dot over scalar a1 (col c16) ----
        float ze = bz2;
        #pragma unroll
        for (int k = 0; k < 16; ++k) ze = fmaf(sa[k], wz2[k], ze);
        ze = fmaxf(ze, 0.0f);
        float sze[16];
        #pragma unroll
        for (int j = 0; j < 16; ++j) sze[j] = rdlane(ze, j);     // z_e -> scalars

        // ---- RNN: pre = ihp + ze.Wih[32:48] + h.Whh (all-scalar operands) ----
        const bool hi = (p & 1);
        float pre = 0.0f;
        #pragma unroll
        for (int i = 0; i < 8; ++i) {
            const float vz = hi ? sze[8 + i] : sze[i];
            const float vh = hi ? hs[8 + i]  : hs[i];
            const float v  = (p < 2) ? vz : vh;
            pre = fmaf(v, wr[i], pre);
        }
        pre += qxor1(pre); pre += qxor2(pre);
        hn = ftanh(pre + ihg);                          // h'[idx], replicated in quad

        #pragma unroll
        for (int k = 0; k < 16; ++k) hs[k] = rdlane(hn, 4 * k);  // h -> scalars

        f2 = nf2; d1 = nd1; ev = nev;
    }

    // ---- h carry-out / final output ----
    if (t0 + T >= L_STEPS) {
        if (p == 0) out[(size_t)L_STEPS * BATCH * 8 * 2 + (size_t)r * 16 + idx] = hn;
    } else {
        if (p == 0) wsh[r * 16 + idx] = hn;
    }
}

// ===================== Fallback: proven round-2 kernel (ws too small) =====================
__global__ __launch_bounds__(64, 1) void vrnn_scan(
    const float* __restrict__ ext, const float* __restrict__ obs, const float* __restrict__ eps,
    const float* __restrict__ puW1, const float* __restrict__ pub1,
    const float* __restrict__ puW2, const float* __restrict__ pub2,
    const float* __restrict__ pxW1, const float* __restrict__ pxb1,
    const float* __restrict__ pxW2, const float* __restrict__ pxb2,
    const float* __restrict__ pzW1, const float* __restrict__ pzb1,
    const float* __restrict__ pzW2, const float* __restrict__ pzb2,
    const float* __restrict__ poW1, const float* __restrict__ pob1,
    const float* __restrict__ poW2, const float* __restrict__ pob2,
    const float* __restrict__ Wmu, const float* __restrict__ bmu,
    const float* __restrict__ Wls, const float* __restrict__ bls,
    const float* __restrict__ Wih, const float* __restrict__ bih,
    const float* __restrict__ Whh, const float* __restrict__ bhh,
    float* __restrict__ out)
{
    const int l   = threadIdx.x;
    const int r   = blockIdx.x;
    const int idx = l >> 2;
    const int p   = l & 3;

    __shared__ __align__(16) float rawbuf[16];
    __shared__ __align__(16) float epsbuf[8];
    __shared__ __align__(16) float h1buf[32];
    __shared__ __align__(16) float in64[64];
    __shared__ __align__(16) float s2buf[48];
    __shared__ __align__(16) float t48[48];
    __shared__ __align__(16) float zbuf[8];
    __shared__ __align__(16) float ze1buf[16];
    __shared__ float bheadb[16];
    __shared__ float brnnb[16];

    if (l < 16) {
        rawbuf[l]    = 0.0f;
        in64[48 + l] = 0.0f;
        bheadb[l]    = (l < 8) ? bmu[l] : bls[l - 8];
        brnnb[l]     = bih[l] + bhh[l];
    }

    float wA[48]; float biasA;
    {
        const float* baseA;
        if (l < 48) { baseA = poW1 + l;        biasA = pob1[l]; }
        else        { baseA = poW2 + (l - 48); biasA = pob2[l - 48]; }
        #pragma unroll
        for (int k = 0; k < 48; ++k) wA[k] = baseA[k * 48];
    }
    float wB[48]; float biasB;
    {
        const int c = 16 + (l & 31);
        const float* baseB = poW2 + c;
        biasB = pob2[c];
        #pragma unroll
        for (int k = 0; k < 48; ++k) wB[k] = baseB[k * 48];
    }
    float whead[12];
    {
        const float* baseH = (idx < 8) ? (Wmu + idx) : (Wls + (idx - 8));
        #pragma unroll
        for (int i = 0; i < 12; ++i) whead[i] = baseH[(12 * p + i) * 8];
    }
    float wrnn[16];
    {
        #pragma unroll
        for (int i = 0; i < 16; ++i) {
            const int c = 16 * p + i;
            const float a = Wih[min(c, 47) * 16 + idx];
            const float b = Whh[max(c - 48, 0) * 16 + idx];
            wrnn[i] = (c < 48) ? a : b;
        }
    }
    const int j16 = l & 15;
    float wpre1[8], wpre2[16], bpre1, bpre2;
    {
        const bool isx = (l < 16);
        #pragma unroll
        for (int k = 0; k < 8; ++k) {
            const float xv = pxW1[min(k, 3) * 16 + j16];
            const float uv = puW1[k * 16 + j16];
            float v = isx ? xv : uv;
            if (isx && k >= 4) v = 0.0f;
            wpre1[k] = v;
        }
        #pragma unroll
        for (int k = 0; k < 16; ++k) {
            const float xv = pxW2[k * 16 + j16];
            const float uv = puW2[k * 16 + j16];
            wpre2[k] = isx ? xv : uv;
        }
        bpre1 = isx ? pxb1[j16] : pub1[j16];
        bpre2 = isx ? pxb2[j16] : pub2[j16];
    }
    float wpz1[8], wpz2[16], bpz1, bpz2;
    {
        #pragma unroll
        for (int k = 0; k < 8; ++k)  wpz1[k] = pzW1[k * 16 + j16];
        #pragma unroll
        for (int k = 0; k < 16; ++k) wpz2[k] = pzW2[k * 16 + j16];
        bpz1 = pzb1[j16];
        bpz2 = pzb2[j16];
    }

    const float* pin; long pstride;
    if (l < 4)                  { pin = obs + (size_t)r * 4 + l;        pstride = 4 * BATCH; }
    else if (l >= 8 && l < 16)  { pin = ext + (size_t)r * 8 + (l - 8);  pstride = 8 * BATCH; }
    else if (l >= 16 && l < 24) { pin = eps + (size_t)r * 8 + (l - 16); pstride = 8 * BATCH; }
    else                        { pin = obs;                            pstride = 0; }

    float vin = *pin;
    pin += pstride;

    float* pout = out + ((idx < 8) ? ((size_t)r * 8 + idx)
                                   : ((size_t)L_STEPS * BATCH * 8 + (size_t)r * 8 + (idx - 8)));

    __syncthreads();

    float hn = 0.0f;

    for (int t = 0; t < L_STEPS; ++t) {
        if (l < 4 || (l >= 8 && l < 16)) rawbuf[l] = vin;
        if (l >= 16 && l < 24)           epsbuf[l - 16] = vin;
        vin = *pin;
        pin += (t < L_STEPS - 2) ? pstride : 0;

        {
            const float4* rb = (const float4*)(rawbuf + ((l & 16) ? 8 : 0));
            float4 v0 = rb[0], v1 = rb[1];
            float a1 = bpre1;
            FMA4(v0, wpre1, 0, a1);
            FMA4(v1, wpre1, 4, a1);
            a1 = fmaxf(a1, 0.0f);
            if (l < 32) h1buf[l] = a1;
            const float4* hb = (const float4*)(h1buf + ((l & 16) ? 16 : 0));
            float a2 = bpre2;
            #pragma unroll
            for (int q = 0; q < 4; ++q) { float4 v = hb[q]; FMA4(v, wpre2, 4 * q, a2); }
            a2 = fmaxf(a2, 0.0f);
            if (l < 32) in64[l] = a2;
        }

        float sA = biasA, sB = biasB;
        {
            const float4* c4 = (const float4*)in64;
            #pragma unroll
            for (int q = 0; q < 8; ++q) {
                float4 v = c4[q];
                FMA4(v, wA, 4 * q, sA);
                FMA4(v, wB, 4 * q, sB);
            }
            const float4* h4 = (const float4*)(in64 + 48);
            #pragma unroll
            for (int q = 0; q < 4; ++q) {
                float4 v = h4[q];
                FMA4(v, wA, 32 + 4 * q, sA);
                FMA4(v, wB, 32 + 4 * q, sB);
            }
        }
        if (l >= 48) s2buf[l - 48] = sA;
        if (l < 32)  s2buf[16 + l] = sB;
        if (l < 48)  t48[l] = ftanh(sA) * fsig(s2buf[l]);

        float acc = 0.0f;
        {
            const float4* tb = (const float4*)(t48 + 12 * p);
            float4 a0 = tb[0], a1v = tb[1], a2v = tb[2];
            FMA4(a0,  whead, 0, acc);
            FMA4(a1v, whead, 4, acc);
            FMA4(a2v, whead, 8, acc);
        }
        acc += __shfl_xor(acc, 1);
        acc += __shfl_xor(acc, 2);
        acc += bheadb[idx];
        if (p == 0) *pout = acc;
        pout += (size_t)8 * BATCH;

        {
            float lsv = __shfl(acc, l | 32);
            if (l < 32) {
                float z = fmaf(__expf(0.5f * lsv), epsbuf[idx], acc);
                if (p == 0) zbuf[idx] = z;
            }
        }

        {
            const float4* zb = (const float4*)zbuf;
            float4 z0 = zb[0], z1 = zb[1];
            float a1 = bpz1;
            FMA4(z0, wpz1, 0, a1);
            FMA4(z1, wpz1, 4, a1);
            a1 = fmaxf(a1, 0.0f);
            if (l < 16) ze1buf[l] = a1;
            const float4* zeb = (const float4*)ze1buf;
            float a2 = bpz2;
            #pragma unroll
            for (int q = 0; q < 4; ++q) { float4 v = zeb[q]; FMA4(v, wpz2, 4 * q, a2); }
            a2 = fmaxf(a2, 0.0f);
            if (l < 16) in64[32 + l] = a2;
        }

        {
            const float4* ib = (const float4*)(in64 + 16 * p);
            float a = 0.0f;
            #pragma unroll
            for (int q = 0; q < 4; ++q) { float4 v = ib[q]; FMA4(v, wrnn, 4 * q, a); }
            a += __shfl_xor(a, 1);
            a += __shfl_xor(a, 2);
            a += brnnb[idx];
            hn = ftanh(a);
            if (p == 0) in64[48 + idx] = hn;
        }
    }

    if (p == 0) out[(size_t)L_STEPS * BATCH * 8 * 2 + (size_t)r * 16 + idx] = hn;
}

extern "C" void kernel_launch(void* const* d_in, const int* in_sizes, int n_in,
                              void* d_out, int out_size, void* d_ws, size_t ws_size,
                              hipStream_t stream) {
    const float* ext  = (const float*)d_in[0];
    const float* obs  = (const float*)d_in[1];
    const float* eps  = (const float*)d_in[2];
    const float* puW1 = (const float*)d_in[3];  const float* pub1 = (const float*)d_in[4];
    const float* puW2 = (const float*)d_in[5];  const float* pub2 = (const float*)d_in[6];
    const float* pxW1 = (const float*)d_in[7];  const float* pxb1 = (const float*)d_in[8];
    const float* pxW2 = (const float*)d_in[9];  const float* pxb2 = (const float*)d_in[10];
    const float* pzW1 = (const float*)d_in[11]; const float* pzb1 = (const float*)d_in[12];
    const float* pzW2 = (const float*)d_in[13]; const float* pzb2 = (const float*)d_in[14];
    const float* poW1 = (const float*)d_in[15]; const float* pob1 = (const float*)d_in[16];
    const float* poW2 = (const float*)d_in[17]; const float* pob2 = (const float*)d_in[18];
    const float* Wmu  = (const float*)d_in[19]; const float* bmu  = (const float*)d_in[20];
    const float* Wls  = (const float*)d_in[21]; const float* bls  = (const float*)d_in[22];
    const float* Wih  = (const float*)d_in[23]; const float* bih  = (const float*)d_in[24];
    const float* Whh  = (const float*)d_in[25]; const float* bhh  = (const float*)d_in[26];
    float* out = (float*)d_out;

    // chunked workspace: [0, 64KB) h-carry, then per-step records of RECF floats
    const size_t hfloats = (size_t)BATCH * 16;                       // 64 KB
    const size_t perstep = (size_t)BATCH * RECF * sizeof(float);     // 458,752 B
    long tc = 0;
    if (ws_size > hfloats * sizeof(float))
        tc = (long)((ws_size - hfloats * sizeof(float)) / perstep);
    if (tc > L_STEPS) tc = L_STEPS;

    if (tc >= 1) {
        float* wsh = (float*)d_ws;
        float* rec = wsh + hfloats;
        for (int t0 = 0; t0 < L_STEPS; t0 += (int)tc) {
            const int T = (L_STEPS - t0 < (int)tc) ? (L_STEPS - t0) : (int)tc;
            vrnn_pre<<<dim3(BATCH / 128, T), dim3(128), 0, stream>>>(
                ext, obs, puW1, pub1, puW2, pub2, pxW1, pxb1, pxW2, pxb2,
                poW1, pob1, poW2, pob2, Wih, bih, bhh, rec, t0);
            vrnn_scan2<<<dim3(BATCH), dim3(64), 0, stream>>>(
                rec, wsh, eps, poW1, poW2, Wmu, bmu, Wls, bls,
                pzW1, pzb1, pzW2, pzb2, Wih, Whh, out, t0, T);
        }
    } else {
        vrnn_scan<<<dim3(BATCH), dim3(64), 0, stream>>>(
            ext, obs, eps,
            puW1, pub1, puW2, pub2,
            pxW1, pxb1, pxW2, pxb2,
            pzW1, pzb1, pzW2, pzb2,
            poW1, pob1, poW2, pob2,
            Wmu, bmu, Wls, bls,
            Wih, bih, Whh, bhh,
            out);
    }
}

// Round 11
// 1655.836 us; speedup vs baseline: 1.3495x; 1.2438x over previous
//
#include <hip/hip_runtime.h>

#define L_STEPS 1000
#define BATCH   1024
#define RECF    112   // floats per (t,r) record: [0:96) s1p/s2p interleaved, [96:112) ihp

__device__ __forceinline__ float frcp(float x)  { return __builtin_amdgcn_rcpf(x); }
__device__ __forceinline__ float fsig(float x)  { return frcp(1.0f + __expf(-x)); }
__device__ __forceinline__ float ftanh(float x) { return 1.0f - 2.0f * frcp(__expf(2.0f * x) + 1.0f); }

// quad_perm DPP cross-lane adds (lanes within each 4-lane group)
__device__ __forceinline__ float qxor1(float x) {
    return __int_as_float(__builtin_amdgcn_update_dpp(0, __float_as_int(x), 0xB1, 0xF, 0xF, true));
}
__device__ __forceinline__ float qxor2(float x) {
    return __int_as_float(__builtin_amdgcn_update_dpp(0, __float_as_int(x), 0x4E, 0xF, 0xF, true));
}

#define FMA4(vv, W, base, A) do { \
    A = fmaf((vv).x, W[(base)+0], A); \
    A = fmaf((vv).y, W[(base)+1], A); \
    A = fmaf((vv).z, W[(base)+2], A); \
    A = fmaf((vv).w, W[(base)+3], A); } while (0)

// ===================== Kernel A: parallel precompute (one time-chunk) =====================
__global__ __launch_bounds__(128) void vrnn_pre(
    const float* __restrict__ ext, const float* __restrict__ obs,
    const float* __restrict__ puW1, const float* __restrict__ pub1,
    const float* __restrict__ puW2, const float* __restrict__ pub2,
    const float* __restrict__ pxW1, const float* __restrict__ pxb1,
    const float* __restrict__ pxW2, const float* __restrict__ pxb2,
    const float* __restrict__ poW1, const float* __restrict__ pob1,
    const float* __restrict__ poW2, const float* __restrict__ pob2,
    const float* __restrict__ Wih, const float* __restrict__ bih,
    const float* __restrict__ bhh,
    float* __restrict__ rec, int t0)
{
    const int j  = threadIdx.x;
    const int rc = blockIdx.x * 128;
    const int tl = blockIdx.y;                 // local step in chunk

    __shared__ float wsm[768];        // px/pu weights+biases staged
    __shared__ float xu[128][36];     // xe|ue per row (padded stride)

    for (int i = j; i < 64;  i += 128) wsm[0   + i] = pxW1[i];
    for (int i = j; i < 256; i += 128) wsm[64  + i] = pxW2[i];
    for (int i = j; i < 128; i += 128) wsm[320 + i] = puW1[i];
    for (int i = j; i < 256; i += 128) wsm[448 + i] = puW2[i];
    if (j < 16) {
        wsm[704 + j] = pxb1[j]; wsm[720 + j] = pxb2[j];
        wsm[736 + j] = pub1[j]; wsm[752 + j] = pub2[j];
    }
    __syncthreads();

    // ---- phase 1: xe/ue for row r = rc + j at global step t0+tl ----
    {
        const size_t row = (size_t)(t0 + tl) * BATCH + rc + j;
        const float* o = obs + row * 4;
        const float* e = ext + row * 8;
        float ob[4], ex[8];
        #pragma unroll
        for (int k = 0; k < 4; ++k) ob[k] = o[k];
        #pragma unroll
        for (int k = 0; k < 8; ++k) ex[k] = e[k];

        float t1[16];
        #pragma unroll
        for (int c = 0; c < 16; ++c) {
            float a = wsm[704 + c];
            #pragma unroll
            for (int k = 0; k < 4; ++k) a = fmaf(ob[k], wsm[0 + k * 16 + c], a);
            t1[c] = fmaxf(a, 0.0f);
        }
        #pragma unroll
        for (int c = 0; c < 16; ++c) {
            float a = wsm[720 + c];
            #pragma unroll
            for (int k = 0; k < 16; ++k) a = fmaf(t1[k], wsm[64 + k * 16 + c], a);
            xu[j][c] = fmaxf(a, 0.0f);                    // xe
        }
        #pragma unroll
        for (int c = 0; c < 16; ++c) {
            float a = wsm[736 + c];
            #pragma unroll
            for (int k = 0; k < 8; ++k) a = fmaf(ex[k], wsm[320 + k * 16 + c], a);
            t1[c] = fmaxf(a, 0.0f);
        }
        #pragma unroll
        for (int c = 0; c < 16; ++c) {
            float a = wsm[752 + c];
            #pragma unroll
            for (int k = 0; k < 16; ++k) a = fmaf(t1[k], wsm[448 + k * 16 + c], a);
            xu[j][16 + c] = fmaxf(a, 0.0f);               // ue
        }
    }

    // ---- phase 2: weight column for record element j (j < 112) ----
    float wc[32]; float bias = 0.0f;
    if (j < 96) {
        const int c = j >> 1;
        const float* W = (j & 1) ? poW2 : poW1;
        bias = (j & 1) ? pob2[c] : pob1[c];
        #pragma unroll
        for (int k = 0; k < 32; ++k) wc[k] = W[k * 48 + c];
    } else if (j < 112) {
        const int c = j - 96;
        bias = bih[c] + bhh[c];
        #pragma unroll
        for (int k = 0; k < 32; ++k) wc[k] = Wih[k * 16 + c];
    }
    __syncthreads();

    if (j < 112) {
        float* rb = rec + ((size_t)tl * BATCH + rc) * RECF + j;
        for (int r = 0; r < 128; ++r) {
            const float4* x4 = (const float4*)&xu[r][0];
            float a = bias;
            #pragma unroll
            for (int q = 0; q < 8; ++q) { float4 v = x4[q]; FMA4(v, wc, 4 * q, a); }
            rb[(size_t)r * RECF] = a;
        }
    }
}

// ===================== Kernel B: register-only serial scan (one time-chunk) =====================
// R7 structure (shfl gathers + DPP quad reductions); ONLY change: the RNN h-access
// is a static 2-way select, never a runtime index (rule-#20 fix).
__global__ __launch_bounds__(64, 1) void vrnn_scan2(
    const float* __restrict__ rec, float* wsh, const float* __restrict__ eps,
    const float* __restrict__ poW1, const float* __restrict__ poW2,
    const float* __restrict__ Wmu, const float* __restrict__ bmu,
    const float* __restrict__ Wls, const float* __restrict__ bls,
    const float* __restrict__ pzW1, const float* __restrict__ pzb1,
    const float* __restrict__ pzW2, const float* __restrict__ pzb2,
    const float* __restrict__ Wih, const float* __restrict__ Whh,
    float* __restrict__ out, int t0, int T)
{
    const int l   = threadIdx.x;
    const int r   = blockIdx.x;
    const int idx = l >> 2;
    const int p   = l & 3;

    // ---- weights -> registers (all statically indexed) ----
    const int cl = (l < 48) ? l : 47;            // safe dummy col for lanes 48-63
    float wAh[16], wBh[16];
    #pragma unroll
    for (int k = 0; k < 16; ++k) {
        wAh[k] = poW1[(32 + k) * 48 + cl];
        wBh[k] = poW2[(32 + k) * 48 + cl];
    }
    const int hm = idx & 7;
    const float* WH = (idx < 8) ? Wmu : Wls;
    float whead[12];
    #pragma unroll
    for (int i = 0; i < 12; ++i) whead[i] = WH[(12 * p + i) * 8 + hm];
    const float bhead = (idx < 8) ? bmu[hm] : bls[hm];

    float wr[8];
    #pragma unroll
    for (int i = 0; i < 8; ++i)
        wr[i] = (p < 2) ? Wih[(32 + 8 * (p & 1) + i) * 16 + idx]
                        : Whh[(8 * (p & 1) + i) * 16 + idx];

    const float wz1a = pzW1[(2 * p) * 16 + idx];
    const float wz1b = pzW1[(2 * p + 1) * 16 + idx];
    const float bz1  = pzb1[idx];
    float wz2[4];
    #pragma unroll
    for (int i = 0; i < 4; ++i) wz2[i] = pzW2[(4 * p + i) * 16 + idx];
    const float bz2 = pzb2[idx];

    // ---- stream pointers (record index local to chunk; eps global) ----
    const float* recp = rec + (size_t)r * RECF + ((l < 48) ? 2 * l : 48 + l);
    const size_t rstride = (size_t)BATCH * RECF;
    const float* epsp = eps + ((size_t)t0 * BATCH + r) * 8 + (l & 7);

    float2 f2 = make_float2(0.0f, 0.0f); float d1 = 0.0f;
    if (l < 48) f2 = *(const float2*)recp; else d1 = *recp;
    float ev = *epsp;
    recp += rstride; epsp += (size_t)8 * BATCH;

    float* pout = out + (size_t)t0 * BATCH * 8
                      + ((idx < 8) ? ((size_t)r * 8 + idx)
                                   : ((size_t)L_STEPS * BATCH * 8 + (size_t)r * 8 + (idx - 8)));

    // ---- h carry-in ----
    float hn = (t0 == 0) ? 0.0f : wsh[r * 16 + idx];
    float h[16];
    #pragma unroll
    for (int k = 0; k < 16; ++k) h[k] = 0.0f;

    for (int t = 0; t < T; ++t) {
        const float s1p = f2.x, s2p = f2.y;
        const float ihpv = d1, epsv = ev;

        // issue next-step prefetch (independent of chain)
        float2 nf2 = make_float2(0.0f, 0.0f); float nd1 = 0.0f;
        if (l < 48) nf2 = *(const float2*)recp; else nd1 = *recp;
        float nev = *epsp;
        recp += (t < T - 2) ? rstride : 0;
        epsp += ((t0 + t) < L_STEPS - 2) ? (size_t)8 * BATCH : 0;

        // off-critical-path gathers (issue early)
        const float ihg = __shfl(ihpv, 48 + idx);       // ihp[idx] from lanes 48-63
        const float eg  = __shfl(epsv, idx & 7);        // eps[idx] from lanes 0-7

        // ---- DBlock: sA/sB = precomputed + h-part ----
        #pragma unroll
        for (int k = 0; k < 16; ++k) h[k] = __shfl(hn, 4 * k);   // static writes, const lanes
        float sA = s1p, sB = s2p;
        #pragma unroll
        for (int k = 0; k < 16; ++k) {
            sA = fmaf(h[k], wAh[k], sA);
            sB = fmaf(h[k], wBh[k], sB);
        }
        const float tt = ftanh(sA) * fsig(sB);          // t48 col l (valid l<48)

        // ---- heads: 4-lane-split dot-48 via shfl gathers ----
        float acc = 0.0f;
        #pragma unroll
        for (int i = 0; i < 12; ++i) acc = fmaf(__shfl(tt, 12 * p + i), whead[i], acc);
        acc += qxor1(acc); acc += qxor2(acc);           // replicated quad sum
        acc += bhead;                                   // mu[idx] (idx<8) | ls[idx-8]
        if (p == 0) *pout = acc;
        pout += (size_t)8 * BATCH;

        // ---- z = mu + exp(0.5 ls)*eps (valid lanes < 32, replicated per quad) ----
        const float other = __shfl(acc, l ^ 32);
        const float zv = fmaf(__expf(0.5f * other), eg, acc);

        // ---- z_e layer 1: 8 -> 16 ----
        float a1 = fmaf(__shfl(zv, 8 * p), wz1a, __shfl(zv, 8 * p + 4) * wz1b);
        a1 += qxor1(a1); a1 += qxor2(a1);
        a1 = fmaxf(a1 + bz1, 0.0f);                     // a1[idx], replicated

        // ---- z_e layer 2: 16 -> 16 ----
        float ze = 0.0f;
        #pragma unroll
        for (int i = 0; i < 4; ++i) ze = fmaf(__shfl(a1, 16 * p + 4 * i), wz2[i], ze);
        ze += qxor1(ze); ze += qxor2(ze);
        ze = fmaxf(ze + bz2, 0.0f);                     // ze[idx], replicated

        // ---- RNN: pre = ihp + ze.Wih[32:48] + h.Whh ----
        // STATIC h access: (p&1) selects between two statically-indexed values.
        const bool hi = (p & 1);
        float pre = 0.0f;
        #pragma unroll
        for (int i = 0; i < 8; ++i) {
            const float g  = __shfl(ze, 4 * (8 * (p & 1) + i));
            const float vh = hi ? h[8 + i] : h[i];
            const float v  = (p < 2) ? g : vh;
            pre = fmaf(v, wr[i], pre);
        }
        pre += qxor1(pre); pre += qxor2(pre);
        hn = ftanh(pre + ihg);                          // h'[idx], replicated in all lanes

        f2 = nf2; d1 = nd1; ev = nev;
    }

    // ---- h carry-out / final output ----
    if (t0 + T >= L_STEPS) {
        if (p == 0) out[(size_t)L_STEPS * BATCH * 8 * 2 + (size_t)r * 16 + idx] = hn;
    } else {
        if (p == 0) wsh[r * 16 + idx] = hn;
    }
}

// ===================== Fallback: proven round-2 kernel (ws too small) =====================
__global__ __launch_bounds__(64, 1) void vrnn_scan(
    const float* __restrict__ ext, const float* __restrict__ obs, const float* __restrict__ eps,
    const float* __restrict__ puW1, const float* __restrict__ pub1,
    const float* __restrict__ puW2, const float* __restrict__ pub2,
    const float* __restrict__ pxW1, const float* __restrict__ pxb1,
    const float* __restrict__ pxW2, const float* __restrict__ pxb2,
    const float* __restrict__ pzW1, const float* __restrict__ pzb1,
    const float* __restrict__ pzW2, const float* __restrict__ pzb2,
    const float* __restrict__ poW1, const float* __restrict__ pob1,
    const float* __restrict__ poW2, const float* __restrict__ pob2,
    const float* __restrict__ Wmu, const float* __restrict__ bmu,
    const float* __restrict__ Wls, const float* __restrict__ bls,
    const float* __restrict__ Wih, const float* __restrict__ bih,
    const float* __restrict__ Whh, const float* __restrict__ bhh,
    float* __restrict__ out)
{
    const int l   = threadIdx.x;
    const int r   = blockIdx.x;
    const int idx = l >> 2;
    const int p   = l & 3;

    __shared__ __align__(16) float rawbuf[16];
    __shared__ __align__(16) float epsbuf[8];
    __shared__ __align__(16) float h1buf[32];
    __shared__ __align__(16) float in64[64];
    __shared__ __align__(16) float s2buf[48];
    __shared__ __align__(16) float t48[48];
    __shared__ __align__(16) float zbuf[8];
    __shared__ __align__(16) float ze1buf[16];
    __shared__ float bheadb[16];
    __shared__ float brnnb[16];

    if (l < 16) {
        rawbuf[l]    = 0.0f;
        in64[48 + l] = 0.0f;
        bheadb[l]    = (l < 8) ? bmu[l] : bls[l - 8];
        brnnb[l]     = bih[l] + bhh[l];
    }

    float wA[48]; float biasA;
    {
        const float* baseA;
        if (l < 48) { baseA = poW1 + l;        biasA = pob1[l]; }
        else        { baseA = poW2 + (l - 48); biasA = pob2[l - 48]; }
        #pragma unroll
        for (int k = 0; k < 48; ++k) wA[k] = baseA[k * 48];
    }
    float wB[48]; float biasB;
    {
        const int c = 16 + (l & 31);
        const float* baseB = poW2 + c;
        biasB = pob2[c];
        #pragma unroll
        for (int k = 0; k < 48; ++k) wB[k] = baseB[k * 48];
    }
    float whead[12];
    {
        const float* baseH = (idx < 8) ? (Wmu + idx) : (Wls + (idx - 8));
        #pragma unroll
        for (int i = 0; i < 12; ++i) whead[i] = baseH[(12 * p + i) * 8];
    }
    float wrnn[16];
    {
        #pragma unroll
        for (int i = 0; i < 16; ++i) {
            const int c = 16 * p + i;
            const float a = Wih[min(c, 47) * 16 + idx];
            const float b = Whh[max(c - 48, 0) * 16 + idx];
            wrnn[i] = (c < 48) ? a : b;
        }
    }
    const int j16 = l & 15;
    float wpre1[8], wpre2[16], bpre1, bpre2;
    {
        const bool isx = (l < 16);
        #pragma unroll
        for (int k = 0; k < 8; ++k) {
            const float xv = pxW1[min(k, 3) * 16 + j16];
            const float uv = puW1[k * 16 + j16];
            float v = isx ? xv : uv;
            if (isx && k >= 4) v = 0.0f;
            wpre1[k] = v;
        }
        #pragma unroll
        for (int k = 0; k < 16; ++k) {
            const float xv = pxW2[k * 16 + j16];
            const float uv = puW2[k * 16 + j16];
            wpre2[k] = isx ? xv : uv;
        }
        bpre1 = isx ? pxb1[j16] : pub1[j16];
        bpre2 = isx ? pxb2[j16] : pub2[j16];
    }
    float wpz1[8], wpz2[16], bpz1, bpz2;
    {
        #pragma unroll
        for (int k = 0; k < 8; ++k)  wpz1[k] = pzW1[k * 16 + j16];
        #pragma unroll
        for (int k = 0; k < 16; ++k) wpz2[k] = pzW2[k * 16 + j16];
        bpz1 = pzb1[j16];
        bpz2 = pzb2[j16];
    }

    const float* pin; long pstride;
    if (l < 4)                  { pin = obs + (size_t)r * 4 + l;        pstride = 4 * BATCH; }
    else if (l >= 8 && l < 16)  { pin = ext + (size_t)r * 8 + (l - 8);  pstride = 8 * BATCH; }
    else if (l >= 16 && l < 24) { pin = eps + (size_t)r * 8 + (l - 16); pstride = 8 * BATCH; }
    else                        { pin = obs;                            pstride = 0; }

    float vin = *pin;
    pin += pstride;

    float* pout = out + ((idx < 8) ? ((size_t)r * 8 + idx)
                                   : ((size_t)L_STEPS * BATCH * 8 + (size_t)r * 8 + (idx - 8)));

    __syncthreads();

    float hn = 0.0f;

    for (int t = 0; t < L_STEPS; ++t) {
        if (l < 4 || (l >= 8 && l < 16)) rawbuf[l] = vin;
        if (l >= 16 && l < 24)           epsbuf[l - 16] = vin;
        vin = *pin;
        pin += (t < L_STEPS - 2) ? pstride : 0;

        {
            const float4* rb = (const float4*)(rawbuf + ((l & 16) ? 8 : 0));
            float4 v0 = rb[0], v1 = rb[1];
            float a1 = bpre1;
            FMA4(v0, wpre1, 0, a1);
            FMA4(v1, wpre1, 4, a1);
            a1 = fmaxf(a1, 0.0f);
            if (l < 32) h1buf[l] = a1;
            const float4* hb = (const float4*)(h1buf + ((l & 16) ? 16 : 0));
            float a2 = bpre2;
            #pragma unroll
            for (int q = 0; q < 4; ++q) { float4 v = hb[q]; FMA4(v, wpre2, 4 * q, a2); }
            a2 = fmaxf(a2, 0.0f);
            if (l < 32) in64[l] = a2;
        }

        float sA = biasA, sB = biasB;
        {
            const float4* c4 = (const float4*)in64;
            #pragma unroll
            for (int q = 0; q < 8; ++q) {
                float4 v = c4[q];
                FMA4(v, wA, 4 * q, sA);
                FMA4(v, wB, 4 * q, sB);
            }
            const float4* h4 = (const float4*)(in64 + 48);
            #pragma unroll
            for (int q = 0; q < 4; ++q) {
                float4 v = h4[q];
                FMA4(v, wA, 32 + 4 * q, sA);
                FMA4(v, wB, 32 + 4 * q, sB);
            }
        }
        if (l >= 48) s2buf[l - 48] = sA;
        if (l < 32)  s2buf[16 + l] = sB;
        if (l < 48)  t48[l] = ftanh(sA) * fsig(s2buf[l]);

        float acc = 0.0f;
        {
            const float4* tb = (const float4*)(t48 + 12 * p);
            float4 a0 = tb[0], a1v = tb[1], a2v = tb[2];
            FMA4(a0,  whead, 0, acc);
            FMA4(a1v, whead, 4, acc);
            FMA4(a2v, whead, 8, acc);
        }
        acc += __shfl_xor(acc, 1);
        acc += __shfl_xor(acc, 2);
        acc += bheadb[idx];
        if (p == 0) *pout = acc;
        pout += (size_t)8 * BATCH;

        {
            float lsv = __shfl(acc, l | 32);
            if (l < 32) {
                float z = fmaf(__expf(0.5f * lsv), epsbuf[idx], acc);
                if (p == 0) zbuf[idx] = z;
            }
        }

        {
            const float4* zb = (const float4*)zbuf;
            float4 z0 = zb[0], z1 = zb[1];
            float a1 = bpz1;
            FMA4(z0, wpz1, 0, a1);
            FMA4(z1, wpz1, 4, a1);
            a1 = fmaxf(a1, 0.0f);
            if (l < 16) ze1buf[l] = a1;
            const float4* zeb = (const float4*)ze1buf;
            float a2 = bpz2;
            #pragma unroll
            for (int q = 0; q < 4; ++q) { float4 v = zeb[q]; FMA4(v, wpz2, 4 * q, a2); }
            a2 = fmaxf(a2, 0.0f);
            if (l < 16) in64[32 + l] = a2;
        }

        {
            const float4* ib = (const float4*)(in64 + 16 * p);
            float a = 0.0f;
            #pragma unroll
            for (int q = 0; q < 4; ++q) { float4 v = ib[q]; FMA4(v, wrnn, 4 * q, a); }
            a += __shfl_xor(a, 1);
            a += __shfl_xor(a, 2);
            a += brnnb[idx];
            hn = ftanh(a);
            if (p == 0) in64[48 + idx] = hn;
        }
    }

    if (p == 0) out[(size_t)L_STEPS * BATCH * 8 * 2 + (size_t)r * 16 + idx] = hn;
}

extern "C" void kernel_launch(void* const* d_in, const int* in_sizes, int n_in,
                              void* d_out, int out_size, void* d_ws, size_t ws_size,
                              hipStream_t stream) {
    const float* ext  = (const float*)d_in[0];
    const float* obs  = (const float*)d_in[1];
    const float* eps  = (const float*)d_in[2];
    const float* puW1 = (const float*)d_in[3];  const float* pub1 = (const float*)d_in[4];
    const float* puW2 = (const float*)d_in[5];  const float* pub2 = (const float*)d_in[6];
    const float* pxW1 = (const float*)d_in[7];  const float* pxb1 = (const float*)d_in[8];
    const float* pxW2 = (const float*)d_in[9];  const float* pxb2 = (const float*)d_in[10];
    const float* pzW1 = (const float*)d_in[11]; const float* pzb1 = (const float*)d_in[12];
    const float* pzW2 = (const float*)d_in[13]; const float* pzb2 = (const float*)d_in[14];
    const float* poW1 = (const float*)d_in[15]; const float* pob1 = (const float*)d_in[16];
    const float* poW2 = (const float*)d_in[17]; const float* pob2 = (const float*)d_in[18];
    const float* Wmu  = (const float*)d_in[19]; const float* bmu  = (const float*)d_in[20];
    const float* Wls  = (const float*)d_in[21]; const float* bls  = (const float*)d_in[22];
    const float* Wih  = (const float*)d_in[23]; const float* bih  = (const float*)d_in[24];
    const float* Whh  = (const float*)d_in[25]; const float* bhh  = (const float*)d_in[26];
    float* out = (float*)d_out;

    // chunked workspace: [0, 64KB) h-carry, then per-step records of RECF floats
    const size_t hfloats = (size_t)BATCH * 16;                       // 64 KB
    const size_t perstep = (size_t)BATCH * RECF * sizeof(float);     // 458,752 B
    long tc = 0;
    if (ws_size > hfloats * sizeof(float))
        tc = (long)((ws_size - hfloats * sizeof(float)) / perstep);
    if (tc > L_STEPS) tc = L_STEPS;

    if (tc >= 1) {
        float* wsh = (float*)d_ws;
        float* rec = wsh + hfloats;
        for (int t0 = 0; t0 < L_STEPS; t0 += (int)tc) {
            const int T = (L_STEPS - t0 < (int)tc) ? (L_STEPS - t0) : (int)tc;
            vrnn_pre<<<dim3(BATCH / 128, T), dim3(128), 0, stream>>>(
                ext, obs, puW1, pub1, puW2, pub2, pxW1, pxb1, pxW2, pxb2,
                poW1, pob1, poW2, pob2, Wih, bih, bhh, rec, t0);
            vrnn_scan2<<<dim3(BATCH), dim3(64), 0, stream>>>(
                rec, wsh, eps, poW1, poW2, Wmu, bmu, Wls, bls,
                pzW1, pzb1, pzW2, pzb2, Wih, Whh, out, t0, T);
        }
    } else {
        vrnn_scan<<<dim3(BATCH), dim3(64), 0, stream>>>(
            ext, obs, eps,
            puW1, pub1, puW2, pub2,
            pxW1, pxb1, pxW2, pxb2,
            pzW1, pzb1, pzW2, pzb2,
            poW1, pob1, poW2, pob2,
            Wmu, bmu, Wls, bls,
            Wih, bih, Whh, bhh,
            out);
    }
}